// Round 1
// baseline (2004.281 us; speedup 1.0000x reference)
//
#include <hip/hip_runtime.h>
#include <math.h>

// Problem constants
#define HWDIM 128
#define DDIM  512
#define ADIM  512
#define NSTEP 6          // min(T=8, LAYER_RANGE+1=6)
#define NPIX  (HWDIM*HWDIM)      // 16384

// ---------------- fp32 tiled GEMM: C[M,512] = X[M,512] @ W[512,512] -------------
// grid: (M/128, 4), block: 256 threads, 8x8 micro-tile per thread.
constexpr int BM = 128, BN = 128, BK = 16;

__global__ __launch_bounds__(256, 2) void gemm_f32(const float* __restrict__ X,
                                                   const float* __restrict__ W,
                                                   float* __restrict__ C) {
  constexpr int N = 512, KD = 512;
  __shared__ float As[BK][BM];   // A stored transposed: As[k][m]
  __shared__ float Bs[BK][BN];
  const int r0 = blockIdx.x * BM;
  const int n0 = blockIdx.y * BN;
  const int tid = threadIdx.x;
  const int tx = tid & 15;       // 16 col-threads
  const int ty = tid >> 4;       // 16 row-threads

  float acc[8][8];
#pragma unroll
  for (int a = 0; a < 8; ++a)
#pragma unroll
    for (int b = 0; b < 8; ++b) acc[a][b] = 0.f;

  for (int k0 = 0; k0 < KD; k0 += BK) {
    // Load A tile (128 rows x 16 k) = 512 float4; 2 per thread; transpose into LDS.
#pragma unroll
    for (int l = 0; l < 2; ++l) {
      const int idx = tid + l * 256;
      const int m  = idx >> 2;          // row within tile
      const int c4 = (idx & 3) * 4;     // k offset within tile
      const float4 v = *(const float4*)(X + (size_t)(r0 + m) * KD + k0 + c4);
      As[c4 + 0][m] = v.x;
      As[c4 + 1][m] = v.y;
      As[c4 + 2][m] = v.z;
      As[c4 + 3][m] = v.w;
    }
    // Load B tile (16 k x 128 n) = 512 float4; 2 per thread; direct.
#pragma unroll
    for (int l = 0; l < 2; ++l) {
      const int idx = tid + l * 256;
      const int k = idx >> 5;
      const int c = (idx & 31) * 4;
      *(float4*)(&Bs[k][c]) = *(const float4*)(W + (size_t)(k0 + k) * N + n0 + c);
    }
    __syncthreads();

#pragma unroll
    for (int k = 0; k < BK; ++k) {
      float a[8], b[8];
      *(float4*)&a[0] = *(const float4*)&As[k][ty * 8];
      *(float4*)&a[4] = *(const float4*)&As[k][ty * 8 + 4];
      *(float4*)&b[0] = *(const float4*)&Bs[k][tx * 8];
      *(float4*)&b[4] = *(const float4*)&Bs[k][tx * 8 + 4];
#pragma unroll
      for (int mm = 0; mm < 8; ++mm)
#pragma unroll
        for (int nn = 0; nn < 8; ++nn)
          acc[mm][nn] = fmaf(a[mm], b[nn], acc[mm][nn]);
    }
    __syncthreads();
  }

#pragma unroll
  for (int mm = 0; mm < 8; ++mm) {
    float* cp = C + (size_t)(r0 + ty * 8 + mm) * N + n0 + tx * 8;
    float4 v0 = make_float4(acc[mm][0], acc[mm][1], acc[mm][2], acc[mm][3]);
    float4 v1 = make_float4(acc[mm][4], acc[mm][5], acc[mm][6], acc[mm][7]);
    *(float4*)cp = v0;
    *(float4*)(cp + 4) = v1;
  }
}

// ---------------- neighbor attention ----------------
// One wave per pixel; 4 waves (4 pixels) per 256-thread block.
// Each lane owns 8 contiguous channels (lane*8 .. lane*8+7).
__global__ __launch_bounds__(256) void attn_f32(const float* __restrict__ Q,
                                                const float* __restrict__ Kb,
                                                const float* __restrict__ Vb,
                                                float* __restrict__ O) {
  const int wid  = threadIdx.x >> 6;
  const int lane = threadIdx.x & 63;
  const int p = blockIdx.x * 4 + wid;          // pixel id 0..16383
  const int i = p >> 7;
  const int j = p & 127;
  const float scale = 0.04419417382415922f;    // 1/sqrt(512)

  // Q fragment in registers
  float q[8];
  {
    const float* qp = Q + (size_t)p * ADIM + lane * 8;
    *(float4*)&q[0] = *(const float4*)(qp);
    *(float4*)&q[4] = *(const float4*)(qp + 4);
  }

  // neighbor pixel indices with edge clamp (== pad 'edge' + shift)
  int nb[9];
  {
    const int di[9] = {-1, -1, -1, 0, 0, 0, 1, 1, 1};
    const int dj[9] = {-1, 0, 1, -1, 0, 1, -1, 0, 1};
#pragma unroll
    for (int n = 0; n < 9; ++n) {
      int ni = i + di[n]; ni = ni < 0 ? 0 : (ni > HWDIM - 1 ? HWDIM - 1 : ni);
      int nj = j + dj[n]; nj = nj < 0 ? 0 : (nj > HWDIM - 1 ? HWDIM - 1 : nj);
      nb[n] = ni * HWDIM + nj;
    }
  }

  float acc[8];
#pragma unroll
  for (int c = 0; c < 8; ++c) acc[c] = 0.f;

  for (int t = 0; t < NSTEP; ++t) {
    const float* Kt = Kb + (size_t)t * NPIX * ADIM;
    const float* Vt = Vb + (size_t)t * NPIX * ADIM;

    float s[9];
#pragma unroll
    for (int n = 0; n < 9; ++n) {
      const float* kp = Kt + (size_t)nb[n] * ADIM + lane * 8;
      float kv[8];
      *(float4*)&kv[0] = *(const float4*)(kp);
      *(float4*)&kv[4] = *(const float4*)(kp + 4);
      float part = 0.f;
#pragma unroll
      for (int c = 0; c < 8; ++c) part = fmaf(q[c], kv[c], part);
      // full-wave (64-lane) butterfly reduce
#pragma unroll
      for (int off = 32; off > 0; off >>= 1) part += __shfl_xor(part, off);
      s[n] = part * scale;
    }

    float m = s[0];
#pragma unroll
    for (int n = 1; n < 9; ++n) m = fmaxf(m, s[n]);
    float e[9];
    float sum = 0.f;
#pragma unroll
    for (int n = 0; n < 9; ++n) { e[n] = expf(s[n] - m); sum += e[n]; }
    const float inv = 1.f / sum;

#pragma unroll
    for (int n = 0; n < 9; ++n) {
      const float w = e[n] * inv;
      const float* vp = Vt + (size_t)nb[n] * ADIM + lane * 8;
      float vv[8];
      *(float4*)&vv[0] = *(const float4*)(vp);
      *(float4*)&vv[4] = *(const float4*)(vp + 4);
#pragma unroll
      for (int c = 0; c < 8; ++c) acc[c] = fmaf(w, vv[c], acc[c]);
    }
  }

  const float invT = 1.f / (float)NSTEP;
  float* op = O + (size_t)p * ADIM + lane * 8;
  float4 v0 = make_float4(acc[0] * invT, acc[1] * invT, acc[2] * invT, acc[3] * invT);
  float4 v1 = make_float4(acc[4] * invT, acc[5] * invT, acc[6] * invT, acc[7] * invT);
  *(float4*)op = v0;
  *(float4*)(op + 4) = v1;
}

// ---------------- launch ----------------
extern "C" void kernel_launch(void* const* d_in, const int* in_sizes, int n_in,
                              void* d_out, int out_size, void* d_ws, size_t ws_size,
                              hipStream_t stream) {
  const float* qf   = (const float*)d_in[0];  // (128,128,512)
  const float* hist = (const float*)d_in[1];  // (8,128,128,512)
  const float* Wq   = (const float*)d_in[2];  // (512,512)
  const float* Wk   = (const float*)d_in[3];
  const float* Wv   = (const float*)d_in[4];
  const float* Wo   = (const float*)d_in[5];
  float* out = (float*)d_out;

  // workspace layout (floats)
  float* ws = (float*)d_ws;
  const size_t QN  = (size_t)NPIX * ADIM;          //  8,388,608
  const size_t KVN = (size_t)NSTEP * NPIX * ADIM;  // 50,331,648
  float* Qb = ws;
  float* Kb = Qb + QN;
  float* Vb = Kb + KVN;
  float* AO = Vb + KVN;

  // last 6 of 8 timesteps
  const float* histBase = hist + (size_t)2 * NPIX * DDIM;

  dim3 blk(256);
  // Q projection: M=16384
  gemm_f32<<<dim3(NPIX / BM, ADIM / BN), blk, 0, stream>>>(qf, Wq, Qb);
  // K,V projections: M=98304
  gemm_f32<<<dim3(NSTEP * NPIX / BM, ADIM / BN), blk, 0, stream>>>(histBase, Wk, Kb);
  gemm_f32<<<dim3(NSTEP * NPIX / BM, ADIM / BN), blk, 0, stream>>>(histBase, Wv, Vb);
  // neighbor attention
  attn_f32<<<dim3(NPIX / 4), blk, 0, stream>>>(Qb, Kb, Vb, AO);
  // output projection
  gemm_f32<<<dim3(NPIX / BM, ADIM / BN), blk, 0, stream>>>(AO, Wo, out);
}

// Round 5
// 997.449 us; speedup vs baseline: 2.0094x; 2.0094x over previous
//
#include <hip/hip_runtime.h>
#include <math.h>

#define HWDIM 128
#define DDIM  512
#define ADIM  512
#define NSTEP 6
#define NPIX  (HWDIM*HWDIM)

typedef short bf16x8 __attribute__((ext_vector_type(8)));
typedef float f32x4 __attribute__((ext_vector_type(4)));

__device__ __forceinline__ ushort f32_bf16_rne(float f) {
  unsigned u = __float_as_uint(f);
  unsigned r = (u + 0x7fffu + ((u >> 16) & 1u)) >> 16;
  return (ushort)r;
}
__device__ __forceinline__ float bf16_f32(ushort h) {
  return __uint_as_float(((unsigned)h) << 16);
}
__device__ __forceinline__ void unpack2(unsigned u, float& a, float& b) {
  a = __uint_as_float(u << 16);
  b = __uint_as_float(u & 0xffff0000u);
}

// ---------------- split fp32 -> (hi, lo) bf16 ----------------
__global__ __launch_bounds__(256) void split_f32(const float* __restrict__ in,
                                                 ushort* __restrict__ hi,
                                                 ushort* __restrict__ lo, int n8) {
  for (int i = blockIdx.x * blockDim.x + threadIdx.x; i < n8; i += gridDim.x * blockDim.x) {
    const float4 v0 = ((const float4*)in)[2 * (size_t)i];
    const float4 v1 = ((const float4*)in)[2 * (size_t)i + 1];
    float x[8] = {v0.x, v0.y, v0.z, v0.w, v1.x, v1.y, v1.z, v1.w};
    ushort h[8], l[8];
#pragma unroll
    for (int j = 0; j < 8; ++j) {
      h[j] = f32_bf16_rne(x[j]);
      l[j] = f32_bf16_rne(x[j] - bf16_f32(h[j]));
    }
    *(uint4*)(hi + (size_t)i * 8) = *(uint4*)h;
    *(uint4*)(lo + (size_t)i * 8) = *(uint4*)l;
  }
}

// ---------------- weight transpose + split: W[k][n] -> T[n][k] hi/lo ----------------
__global__ __launch_bounds__(256) void wsplit(const float* __restrict__ W,
                                              ushort* __restrict__ Thi,
                                              ushort* __restrict__ Tlo) {
  __shared__ float tile[32][33];
  const int bn = blockIdx.x * 32, bk = blockIdx.y * 32;
  const int tx = threadIdx.x, ty = threadIdx.y;  // block (32,8)
  for (int r = ty; r < 32; r += 8)
    tile[r][tx] = W[(size_t)(bk + r) * 512 + bn + tx];
  __syncthreads();
  for (int r = ty; r < 32; r += 8) {
    const float x = tile[tx][r];
    const ushort h = f32_bf16_rne(x);
    const ushort l = f32_bf16_rne(x - bf16_f32(h));
    Thi[(size_t)(bn + r) * 512 + bk + tx] = h;
    Tlo[(size_t)(bn + r) * 512 + bk + tx] = l;
  }
}

// ---------------- split-bf16 MFMA GEMM ----------------
// C[M,512] = A[M,512] @ B[512,512], B given pre-transposed as Bt[n][k].
// 128x128 tile, BK=32, 4 waves, each wave 64x64 (4x4 frags of 16x16x32 MFMA).
// LDS tiles are [128 rows][32 k] bf16; 16B slot s of row r holds k-group
// s^((r>>1)&3)  ->  global slot index 4*(r&1) + s^((r>>1)&3) is a bijection
// over 0..7 for any 8 consecutive rows => conflict-free ds_read_b128.
template<int OUT_BF16>
__global__ __launch_bounds__(256, 2) void gemm_split(
    const ushort* __restrict__ Ahi, const ushort* __restrict__ Alo,
    const ushort* __restrict__ Bhi, const ushort* __restrict__ Blo,
    void* __restrict__ Cout) {
  constexpr int KD = 512, N = 512;
  __shared__ uint4 smv[2048];  // 32 KB
  char* sm = (char*)smv;
  const int r0 = blockIdx.x * 128;
  const int n0 = blockIdx.y * 128;
  const int tid = threadIdx.x;
  const int wv = tid >> 6, lane = tid & 63;
  const int wr = wv >> 1, wc = wv & 1;

  f32x4 acc[4][4];
#pragma unroll
  for (int a = 0; a < 4; ++a)
#pragma unroll
    for (int b = 0; b < 4; ++b) acc[a][b] = (f32x4){0.f, 0.f, 0.f, 0.f};

  // staging: call c stages linear bytes [(c*256+tid)*16, +16)
  // idx = c*256+tid; row = idx>>2; slot = idx&3; source k-group = slot^((row>>1)&3)
  int rowS[2], sS[2];
#pragma unroll
  for (int c = 0; c < 2; ++c) {
    const int idx = c * 256 + tid;
    rowS[c] = idx >> 2;
    sS[c] = (idx & 3) ^ ((rowS[c] >> 1) & 3);
  }
  char* smA  = sm;
  char* smAl = sm + 8192;
  char* smB  = sm + 16384;
  char* smBl = sm + 24576;
  const int ldsWave = wv * 1024;

  for (int k0 = 0; k0 < KD; k0 += 32) {
    __syncthreads();
#pragma unroll
    for (int c = 0; c < 2; ++c) {
      const size_t aoff = (size_t)(r0 + rowS[c]) * KD + k0 + sS[c] * 8;
      const size_t boff = (size_t)(n0 + rowS[c]) * KD + k0 + sS[c] * 8;
      const int lds = c * 4096 + ldsWave;
      __builtin_amdgcn_global_load_lds(
          (const __attribute__((address_space(1))) void*)(Ahi + aoff),
          (__attribute__((address_space(3))) void*)(smA + lds), 16, 0, 0);
      __builtin_amdgcn_global_load_lds(
          (const __attribute__((address_space(1))) void*)(Alo + aoff),
          (__attribute__((address_space(3))) void*)(smAl + lds), 16, 0, 0);
      __builtin_amdgcn_global_load_lds(
          (const __attribute__((address_space(1))) void*)(Bhi + boff),
          (__attribute__((address_space(3))) void*)(smB + lds), 16, 0, 0);
      __builtin_amdgcn_global_load_lds(
          (const __attribute__((address_space(1))) void*)(Blo + boff),
          (__attribute__((address_space(3))) void*)(smBl + lds), 16, 0, 0);
    }
    __syncthreads();

    const int kq = lane >> 4;   // k-group 0..3 (8 bf16 each)
    const int fr = lane & 15;   // row within 16x16 frag
    bf16x8 ah[4], al[4], bh[4], bl[4];
#pragma unroll
    for (int mi = 0; mi < 4; ++mi) {
      const int row = wr * 64 + mi * 16 + fr;
      const int off = row * 64 + ((kq ^ ((row >> 1) & 3)) * 16);
      ah[mi] = *(const bf16x8*)(smA + off);
      al[mi] = *(const bf16x8*)(smAl + off);
    }
#pragma unroll
    for (int ni = 0; ni < 4; ++ni) {
      const int row = wc * 64 + ni * 16 + fr;
      const int off = row * 64 + ((kq ^ ((row >> 1) & 3)) * 16);
      bh[ni] = *(const bf16x8*)(smB + off);
      bl[ni] = *(const bf16x8*)(smBl + off);
    }
#pragma unroll
    for (int mi = 0; mi < 4; ++mi)
#pragma unroll
      for (int ni = 0; ni < 4; ++ni) {
        acc[mi][ni] = __builtin_amdgcn_mfma_f32_16x16x32_bf16(ah[mi], bh[ni], acc[mi][ni], 0, 0, 0);
        acc[mi][ni] = __builtin_amdgcn_mfma_f32_16x16x32_bf16(al[mi], bh[ni], acc[mi][ni], 0, 0, 0);
        acc[mi][ni] = __builtin_amdgcn_mfma_f32_16x16x32_bf16(ah[mi], bl[ni], acc[mi][ni], 0, 0, 0);
      }
  }

  const int fr = lane & 15;
  const int rq = lane >> 4;
#pragma unroll
  for (int mi = 0; mi < 4; ++mi)
#pragma unroll
    for (int ni = 0; ni < 4; ++ni) {
      const int col = n0 + wc * 64 + ni * 16 + fr;
#pragma unroll
      for (int r = 0; r < 4; ++r) {
        const int row = r0 + wr * 64 + mi * 16 + rq * 4 + r;
        if (OUT_BF16)
          ((ushort*)Cout)[(size_t)row * N + col] = f32_bf16_rne(acc[mi][ni][r]);
        else
          ((float*)Cout)[(size_t)row * N + col] = acc[mi][ni][r];
      }
    }
}

// ---------------- neighbor attention (bf16 K/V) ----------------
__global__ __launch_bounds__(256) void attn_bf16(const float* __restrict__ Q,
                                                 const ushort* __restrict__ Kb,
                                                 const ushort* __restrict__ Vb,
                                                 ushort* __restrict__ AOhi,
                                                 ushort* __restrict__ AOlo) {
  const int wid = threadIdx.x >> 6;
  const int lane = threadIdx.x & 63;
  const int p = blockIdx.x * 4 + wid;
  const int i = p >> 7, j = p & 127;
  const float scale = 0.04419417382415922f;  // 1/sqrt(512)

  float q[8];
  {
    const float* qp = Q + (size_t)p * ADIM + lane * 8;
    *(float4*)&q[0] = *(const float4*)(qp);
    *(float4*)&q[4] = *(const float4*)(qp + 4);
  }

  int nb[9];
  {
    const int di[9] = {-1, -1, -1, 0, 0, 0, 1, 1, 1};
    const int dj[9] = {-1, 0, 1, -1, 0, 1, -1, 0, 1};
#pragma unroll
    for (int n = 0; n < 9; ++n) {
      int ni = i + di[n]; ni = ni < 0 ? 0 : (ni > 127 ? 127 : ni);
      int nj = j + dj[n]; nj = nj < 0 ? 0 : (nj > 127 ? 127 : nj);
      nb[n] = ni * HWDIM + nj;
    }
  }

  float acc[8];
#pragma unroll
  for (int c = 0; c < 8; ++c) acc[c] = 0.f;

  for (int t = 0; t < NSTEP; ++t) {
    const ushort* Kt = Kb + (size_t)t * NPIX * ADIM;
    const ushort* Vt = Vb + (size_t)t * NPIX * ADIM;

    float s[9];
#pragma unroll
    for (int n = 0; n < 9; ++n) {
      const uint4 raw = *(const uint4*)(Kt + (size_t)nb[n] * ADIM + lane * 8);
      float kv[8];
      unpack2(raw.x, kv[0], kv[1]);
      unpack2(raw.y, kv[2], kv[3]);
      unpack2(raw.z, kv[4], kv[5]);
      unpack2(raw.w, kv[6], kv[7]);
      float part = 0.f;
#pragma unroll
      for (int c = 0; c < 8; ++c) part = fmaf(q[c], kv[c], part);
#pragma unroll
      for (int off = 32; off > 0; off >>= 1) part += __shfl_xor(part, off);
      s[n] = part * scale;
    }

    float m = s[0];
#pragma unroll
    for (int n = 1; n < 9; ++n) m = fmaxf(m, s[n]);
    float e[9];
    float sum = 0.f;
#pragma unroll
    for (int n = 0; n < 9; ++n) { e[n] = expf(s[n] - m); sum += e[n]; }
    const float inv = 1.f / sum;

#pragma unroll
    for (int n = 0; n < 9; ++n) {
      const float w = e[n] * inv;
      const uint4 raw = *(const uint4*)(Vt + (size_t)nb[n] * ADIM + lane * 8);
      float vv[8];
      unpack2(raw.x, vv[0], vv[1]);
      unpack2(raw.y, vv[2], vv[3]);
      unpack2(raw.z, vv[4], vv[5]);
      unpack2(raw.w, vv[6], vv[7]);
#pragma unroll
      for (int c = 0; c < 8; ++c) acc[c] = fmaf(w, vv[c], acc[c]);
    }
  }

  const float invT = 1.f / (float)NSTEP;
  ushort h[8], l[8];
#pragma unroll
  for (int c = 0; c < 8; ++c) {
    const float x = acc[c] * invT;
    h[c] = f32_bf16_rne(x);
    l[c] = f32_bf16_rne(x - bf16_f32(h[c]));
  }
  *(uint4*)(AOhi + (size_t)p * ADIM + lane * 8) = *(uint4*)h;
  *(uint4*)(AOlo + (size_t)p * ADIM + lane * 8) = *(uint4*)l;
}

// ---------------- launch ----------------
extern "C" void kernel_launch(void* const* d_in, const int* in_sizes, int n_in,
                              void* d_out, int out_size, void* d_ws, size_t ws_size,
                              hipStream_t stream) {
  const float* qf   = (const float*)d_in[0];
  const float* hist = (const float*)d_in[1];
  const float* Wq   = (const float*)d_in[2];
  const float* Wk   = (const float*)d_in[3];
  const float* Wv   = (const float*)d_in[4];
  const float* Wo   = (const float*)d_in[5];
  float* out = (float*)d_out;

  const size_t QN  = (size_t)NPIX * ADIM;          //  8,388,608 elems (one image)
  const size_t KVN = (size_t)NSTEP * NPIX * ADIM;  // 50,331,648 elems
  const size_t WN  = 512 * 512;

  // workspace (~307 MB total; well under the 448 MiB proven in round 1)
  size_t off = 0;
  char* base = (char*)d_ws;
  auto alloc = [&](size_t bytes) -> char* {
    char* p = base + off;
    off += (bytes + 255) & ~(size_t)255;
    return p;
  };
  ushort* h_hi  = (ushort*)alloc(QN * 2);   // one timestep, rotating
  ushort* h_lo  = (ushort*)alloc(QN * 2);
  ushort* q_hi  = (ushort*)alloc(QN * 2);
  ushort* q_lo  = (ushort*)alloc(QN * 2);
  ushort* wq_hi = (ushort*)alloc(WN * 2);
  ushort* wq_lo = (ushort*)alloc(WN * 2);
  ushort* wk_hi = (ushort*)alloc(WN * 2);
  ushort* wk_lo = (ushort*)alloc(WN * 2);
  ushort* wv_hi = (ushort*)alloc(WN * 2);
  ushort* wv_lo = (ushort*)alloc(WN * 2);
  ushort* wo_hi = (ushort*)alloc(WN * 2);
  ushort* wo_lo = (ushort*)alloc(WN * 2);
  float*  Qf    = (float*)alloc(QN * 4);
  ushort* Kb    = (ushort*)alloc(KVN * 2);
  ushort* Vb    = (ushort*)alloc(KVN * 2);
  // attention output reuses q_hi/q_lo (dead after the Q projection)
  ushort* ao_hi = q_hi;
  ushort* ao_lo = q_lo;

  const float* histBase = hist + (size_t)2 * NPIX * DDIM;  // last 6 of 8 steps

  dim3 wgrid(16, 16), wblk(32, 8);
  wsplit<<<wgrid, wblk, 0, stream>>>(Wq, wq_hi, wq_lo);
  wsplit<<<wgrid, wblk, 0, stream>>>(Wk, wk_hi, wk_lo);
  wsplit<<<wgrid, wblk, 0, stream>>>(Wv, wv_hi, wv_lo);
  wsplit<<<wgrid, wblk, 0, stream>>>(Wo, wo_hi, wo_lo);

  // Q projection
  split_f32<<<1024, 256, 0, stream>>>(qf, q_hi, q_lo, (int)(QN / 8));
  gemm_split<0><<<dim3(NPIX / 128, 4), 256, 0, stream>>>(q_hi, q_lo, wq_hi, wq_lo, Qf);

  // K/V projections, one timestep at a time (keeps split buffers small & L2-hot)
  for (int t = 0; t < NSTEP; ++t) {
    split_f32<<<1024, 256, 0, stream>>>(histBase + (size_t)t * NPIX * DDIM,
                                        h_hi, h_lo, (int)(QN / 8));
    gemm_split<1><<<dim3(NPIX / 128, 4), 256, 0, stream>>>(
        h_hi, h_lo, wk_hi, wk_lo, Kb + (size_t)t * NPIX * ADIM);
    gemm_split<1><<<dim3(NPIX / 128, 4), 256, 0, stream>>>(
        h_hi, h_lo, wv_hi, wv_lo, Vb + (size_t)t * NPIX * ADIM);
  }

  attn_bf16<<<NPIX / 4, 256, 0, stream>>>(Qf, Kb, Vb, ao_hi, ao_lo);

  gemm_split<0><<<dim3(NPIX / 128, 4), 256, 0, stream>>>(ao_hi, ao_lo, wo_hi, wo_lo, out);
}

// Round 8
// 801.178 us; speedup vs baseline: 2.5017x; 1.2450x over previous
//
#include <hip/hip_runtime.h>
#include <math.h>

#define HWDIM 128
#define DDIM  512
#define ADIM  512
#define NSTEP 6
#define NPIX  (HWDIM*HWDIM)

typedef short bf16x8 __attribute__((ext_vector_type(8)));
typedef float f32x4 __attribute__((ext_vector_type(4)));

__device__ __forceinline__ ushort f32_bf16_rne(float f) {
  unsigned u = __float_as_uint(f);
  unsigned r = (u + 0x7fffu + ((u >> 16) & 1u)) >> 16;
  return (ushort)r;
}
__device__ __forceinline__ float bf16_f32(ushort h) {
  return __uint_as_float(((unsigned)h) << 16);
}
__device__ __forceinline__ void unpack2(unsigned u, float& a, float& b) {
  a = __uint_as_float(u << 16);
  b = __uint_as_float(u & 0xffff0000u);
}

// ---------------- quantize fp32 -> bf16 (rne) ----------------
__global__ __launch_bounds__(256) void quant_bf16(const float* __restrict__ in,
                                                  ushort* __restrict__ out, int n8) {
  for (int i = blockIdx.x * blockDim.x + threadIdx.x; i < n8; i += gridDim.x * blockDim.x) {
    const float4 v0 = ((const float4*)in)[2 * (size_t)i];
    const float4 v1 = ((const float4*)in)[2 * (size_t)i + 1];
    float x[8] = {v0.x, v0.y, v0.z, v0.w, v1.x, v1.y, v1.z, v1.w};
    ushort h[8];
#pragma unroll
    for (int j = 0; j < 8; ++j) h[j] = f32_bf16_rne(x[j]);
    *(uint4*)(out + (size_t)i * 8) = *(uint4*)h;
  }
}

// ---- weight transpose + split (with scale): W[k][n] -> T[n][k] hi/lo ----
__global__ __launch_bounds__(256) void wsplit(const float* __restrict__ W,
                                              ushort* __restrict__ Thi,
                                              ushort* __restrict__ Tlo, float scale) {
  __shared__ float tile[32][33];
  const int bn = blockIdx.x * 32, bk = blockIdx.y * 32;
  const int tx = threadIdx.x, ty = threadIdx.y;  // block (32,8)
  for (int r = ty; r < 32; r += 8)
    tile[r][tx] = W[(size_t)(bk + r) * 512 + bn + tx];
  __syncthreads();
  for (int r = ty; r < 32; r += 8) {
    const float x = tile[tx][r] * scale;
    const ushort h = f32_bf16_rne(x);
    const ushort l = f32_bf16_rne(x - bf16_f32(h));
    Thi[(size_t)(bn + r) * 512 + bk + tx] = h;
    Tlo[(size_t)(bn + r) * 512 + bk + tx] = l;
  }
}

// ---------------- 2-term split GEMM: A bf16, B hi/lo ----------------
// C[M,N'] = A[M,KD] @ B[KD,N'], B pre-transposed [n][k] hi/lo.
// 128x128 tile, BK=32, 4 waves, per-wave 4x4 frags of 16x16x32 MFMA, 2 terms.
// LDS tiles [128 rows][32 k] bf16; 16B slot s of row r holds k-group
// s^((r>>1)&3)  (bijective over 8 slots per 8-row group => conflict-free b128).
// OUT_MODE 0: out1 = float[.][512].  OUT_MODE 1: bf16 dual (n<512 -> out1, else out2).
template<int OUT_MODE, int TSLICES>
__global__ __launch_bounds__(256, 2) void gemm_a1b2(
    const ushort* __restrict__ A, const ushort* __restrict__ Bh,
    const ushort* __restrict__ Bl, void* __restrict__ out1, void* __restrict__ out2) {
  constexpr int KD = 512 * TSLICES;
  constexpr size_t ASLICE = (size_t)NPIX * 512;
  __shared__ uint4 smv[1536];  // 24 KB
  char* sm = (char*)smv;
  const int r0 = blockIdx.x * 128;
  const int n0 = blockIdx.y * 128;
  const int tid = threadIdx.x;
  const int wv = tid >> 6, lane = tid & 63;
  const int wr = wv >> 1, wc = wv & 1;

  f32x4 acc[4][4];
#pragma unroll
  for (int a = 0; a < 4; ++a)
#pragma unroll
    for (int b = 0; b < 4; ++b) acc[a][b] = (f32x4){0.f, 0.f, 0.f, 0.f};

  int rowS[2], sS[2];
#pragma unroll
  for (int c = 0; c < 2; ++c) {
    const int idx = c * 256 + tid;
    rowS[c] = idx >> 2;
    sS[c] = (idx & 3) ^ ((rowS[c] >> 1) & 3);
  }
  char* smA  = sm;
  char* smBh = sm + 8192;
  char* smBl = sm + 16384;
  const int ldsWave = wv * 1024;

  for (int k0 = 0; k0 < KD; k0 += 32) {
    const int kk = k0 & 511;
    const size_t abase = (size_t)(k0 >> 9) * ASLICE;
    __syncthreads();
#pragma unroll
    for (int c = 0; c < 2; ++c) {
      const size_t aoff = abase + (size_t)(r0 + rowS[c]) * 512 + kk + sS[c] * 8;
      const size_t boff = (size_t)(n0 + rowS[c]) * 512 + kk + sS[c] * 8;
      const int lds = c * 4096 + ldsWave;
      __builtin_amdgcn_global_load_lds(
          (const __attribute__((address_space(1))) void*)(A + aoff),
          (__attribute__((address_space(3))) void*)(smA + lds), 16, 0, 0);
      __builtin_amdgcn_global_load_lds(
          (const __attribute__((address_space(1))) void*)(Bh + boff),
          (__attribute__((address_space(3))) void*)(smBh + lds), 16, 0, 0);
      __builtin_amdgcn_global_load_lds(
          (const __attribute__((address_space(1))) void*)(Bl + boff),
          (__attribute__((address_space(3))) void*)(smBl + lds), 16, 0, 0);
    }
    __syncthreads();

    const int kq = lane >> 4;
    const int fr = lane & 15;
    bf16x8 ah[4], bh[4], bl[4];
#pragma unroll
    for (int mi = 0; mi < 4; ++mi) {
      const int row = wr * 64 + mi * 16 + fr;
      const int off = row * 64 + ((kq ^ ((row >> 1) & 3)) * 16);
      ah[mi] = *(const bf16x8*)(smA + off);
    }
#pragma unroll
    for (int ni = 0; ni < 4; ++ni) {
      const int row = wc * 64 + ni * 16 + fr;
      const int off = row * 64 + ((kq ^ ((row >> 1) & 3)) * 16);
      bh[ni] = *(const bf16x8*)(smBh + off);
      bl[ni] = *(const bf16x8*)(smBl + off);
    }
#pragma unroll
    for (int mi = 0; mi < 4; ++mi)
#pragma unroll
      for (int ni = 0; ni < 4; ++ni) {
        acc[mi][ni] = __builtin_amdgcn_mfma_f32_16x16x32_bf16(ah[mi], bh[ni], acc[mi][ni], 0, 0, 0);
        acc[mi][ni] = __builtin_amdgcn_mfma_f32_16x16x32_bf16(ah[mi], bl[ni], acc[mi][ni], 0, 0, 0);
      }
  }

  const int fr = lane & 15;
  const int rq = lane >> 4;
  if (OUT_MODE == 1) {
    ushort* op = (ushort*)(n0 >= 512 ? out2 : out1);
    const int cb = (n0 & 511) + wc * 64;
#pragma unroll
    for (int mi = 0; mi < 4; ++mi)
#pragma unroll
      for (int ni = 0; ni < 4; ++ni) {
        const int col = cb + ni * 16 + fr;
#pragma unroll
        for (int r = 0; r < 4; ++r) {
          const int row = r0 + wr * 64 + mi * 16 + rq * 4 + r;
          op[(size_t)row * 512 + col] = f32_bf16_rne(acc[mi][ni][r]);
        }
      }
  } else {
    float* op = (float*)out1;
    const int cb = n0 + wc * 64;
#pragma unroll
    for (int mi = 0; mi < 4; ++mi)
#pragma unroll
      for (int ni = 0; ni < 4; ++ni) {
        const int col = cb + ni * 16 + fr;
#pragma unroll
        for (int r = 0; r < 4; ++r) {
          const int row = r0 + wr * 64 + mi * 16 + rq * 4 + r;
          op[(size_t)row * 512 + col] = acc[mi][ni][r];
        }
      }
  }
}

// ---------------- neighbor attention, t-split: 6 waves = 6 timesteps ----------------
// block = 384 threads; wave w handles timestep w of pixel blockIdx.x.
// Cross-wave t-sum via swizzled LDS; writes summed AO (bf16). 1/6 folded into Wo.
__global__ __launch_bounds__(384) void attn_t6(const float* __restrict__ Qf,
                                               const ushort* __restrict__ Kb,
                                               const ushort* __restrict__ Vb,
                                               ushort* __restrict__ AOsum) {
  __shared__ float red[6][512];
  const int w = threadIdx.x >> 6;      // timestep
  const int lane = threadIdx.x & 63;
  const int p = blockIdx.x;
  const int i = p >> 7, j = p & 127;
  const float scale = 0.04419417382415922f;  // 1/sqrt(512)

  float q[8];
  {
    const float* qp = Qf + (size_t)p * ADIM + lane * 8;
    *(float4*)&q[0] = *(const float4*)(qp);
    *(float4*)&q[4] = *(const float4*)(qp + 4);
  }

  int nb[9];
  {
    const int di[9] = {-1, -1, -1, 0, 0, 0, 1, 1, 1};
    const int dj[9] = {-1, 0, 1, -1, 0, 1, -1, 0, 1};
#pragma unroll
    for (int n = 0; n < 9; ++n) {
      int ni = i + di[n]; ni = ni < 0 ? 0 : (ni > 127 ? 127 : ni);
      int nj = j + dj[n]; nj = nj < 0 ? 0 : (nj > 127 ? 127 : nj);
      nb[n] = ni * HWDIM + nj;
    }
  }

  const ushort* Kt = Kb + (size_t)w * NPIX * ADIM;
  const ushort* Vt = Vb + (size_t)w * NPIX * ADIM;

  float s[9];
#pragma unroll
  for (int n = 0; n < 9; ++n) {
    const uint4 raw = *(const uint4*)(Kt + (size_t)nb[n] * ADIM + lane * 8);
    float kv[8];
    unpack2(raw.x, kv[0], kv[1]);
    unpack2(raw.y, kv[2], kv[3]);
    unpack2(raw.z, kv[4], kv[5]);
    unpack2(raw.w, kv[6], kv[7]);
    float part = 0.f;
#pragma unroll
    for (int c = 0; c < 8; ++c) part = fmaf(q[c], kv[c], part);
#pragma unroll
    for (int off = 32; off > 0; off >>= 1) part += __shfl_xor(part, off);
    s[n] = part * scale;
  }

  float m = s[0];
#pragma unroll
  for (int n = 1; n < 9; ++n) m = fmaxf(m, s[n]);
  float e[9];
  float sum = 0.f;
#pragma unroll
  for (int n = 0; n < 9; ++n) { e[n] = expf(s[n] - m); sum += e[n]; }
  const float inv = 1.f / sum;

  float acc[8];
#pragma unroll
  for (int c = 0; c < 8; ++c) acc[c] = 0.f;
#pragma unroll
  for (int n = 0; n < 9; ++n) {
    const float wt = e[n] * inv;
    const uint4 raw = *(const uint4*)(Vt + (size_t)nb[n] * ADIM + lane * 8);
    float vv[8];
    unpack2(raw.x, vv[0], vv[1]);
    unpack2(raw.y, vv[2], vv[3]);
    unpack2(raw.z, vv[4], vv[5]);
    unpack2(raw.w, vv[6], vv[7]);
#pragma unroll
    for (int c = 0; c < 8; ++c) acc[c] = fmaf(wt, vv[c], acc[c]);
  }

  // swizzled LDS write: 16B chunk c stored at physical chunk c ^ ((c>>3)&7)
  {
    const int c0 = 2 * lane;
    const int sw = (lane >> 2) & 7;
    *(float4*)&red[w][((c0) ^ sw) * 4]     = make_float4(acc[0], acc[1], acc[2], acc[3]);
    *(float4*)&red[w][((c0 + 1) ^ sw) * 4] = make_float4(acc[4], acc[5], acc[6], acc[7]);
  }
  __syncthreads();

  for (int ch = threadIdx.x; ch < 512; ch += 384) {
    const int cs = (((ch >> 2) ^ ((ch >> 5) & 7)) << 2) | (ch & 3);
    const float t = red[0][cs] + red[1][cs] + red[2][cs] +
                    red[3][cs] + red[4][cs] + red[5][cs];
    AOsum[(size_t)p * ADIM + ch] = f32_bf16_rne(t);
  }
}

// ---------------- launch ----------------
extern "C" void kernel_launch(void* const* d_in, const int* in_sizes, int n_in,
                              void* d_out, int out_size, void* d_ws, size_t ws_size,
                              hipStream_t stream) {
  const float* qf   = (const float*)d_in[0];
  const float* hist = (const float*)d_in[1];
  const float* Wq   = (const float*)d_in[2];
  const float* Wk   = (const float*)d_in[3];
  const float* Wv   = (const float*)d_in[4];
  const float* Wo   = (const float*)d_in[5];
  float* out = (float*)d_out;

  const size_t QN  = (size_t)NPIX * ADIM;          // 8,388,608 elems
  const size_t KVN = (size_t)NSTEP * NPIX * ADIM;  // 50,331,648 elems
  const size_t WN  = 512 * 512;

  // workspace ~278 MB (proven bound 448 MiB from round 1)
  size_t off = 0;
  char* base = (char*)d_ws;
  auto alloc = [&](size_t bytes) -> char* {
    char* p = base + off;
    off += (bytes + 255) & ~(size_t)255;
    return p;
  };
  ushort* h_hi   = (ushort*)alloc(QN * 2);       // rotating per-step hist bf16
  ushort* q_hi   = (ushort*)alloc(QN * 2);
  ushort* wq_hi  = (ushort*)alloc(WN * 2);
  ushort* wq_lo  = (ushort*)alloc(WN * 2);
  ushort* wkv_hi = (ushort*)alloc(2 * WN * 2);   // [1024][512]: rows 0-511 Wk^T, 512-1023 Wv^T
  ushort* wkv_lo = (ushort*)alloc(2 * WN * 2);
  ushort* wo_hi  = (ushort*)alloc(WN * 2);
  ushort* wo_lo  = (ushort*)alloc(WN * 2);
  float*  Qf     = (float*)alloc(QN * 4);
  ushort* Kb     = (ushort*)alloc(KVN * 2);
  ushort* Vb     = (ushort*)alloc(KVN * 2);
  ushort* AOsum  = (ushort*)alloc(QN * 2);

  const float* histBase = hist + (size_t)2 * NPIX * DDIM;  // last 6 of 8 steps

  dim3 wgrid(16, 16), wblk(32, 8);
  wsplit<<<wgrid, wblk, 0, stream>>>(Wq, wq_hi, wq_lo, 1.0f);
  wsplit<<<wgrid, wblk, 0, stream>>>(Wk, wkv_hi, wkv_lo, 1.0f);
  wsplit<<<wgrid, wblk, 0, stream>>>(Wv, wkv_hi + 512 * 512, wkv_lo + 512 * 512, 1.0f);
  wsplit<<<wgrid, wblk, 0, stream>>>(Wo, wo_hi, wo_lo, 1.0f / (float)NSTEP);

  // Q projection (fp32 out)
  quant_bf16<<<1024, 256, 0, stream>>>(qf, q_hi, (int)(QN / 8));
  gemm_a1b2<0, 1><<<dim3(NPIX / 128, 4), 256, 0, stream>>>(q_hi, wq_hi, wq_lo, Qf, nullptr);

  // K|V fused projection, one timestep at a time
  for (int t = 0; t < NSTEP; ++t) {
    quant_bf16<<<1024, 256, 0, stream>>>(histBase + (size_t)t * NPIX * DDIM, h_hi, (int)(QN / 8));
    gemm_a1b2<1, 1><<<dim3(NPIX / 128, 8), 256, 0, stream>>>(
        h_hi, wkv_hi, wkv_lo, Kb + (size_t)t * NPIX * ADIM, Vb + (size_t)t * NPIX * ADIM);
  }

  // attention (t-parallel, block-level t-sum)
  attn_t6<<<NPIX, 384, 0, stream>>>(Qf, Kb, Vb, AOsum);

  // output projection (1/6 folded into wo split)
  gemm_a1b2<0, 1><<<dim3(NPIX / 128, 4), 256, 0, stream>>>(AOsum, wo_hi, wo_lo, out, nullptr);
}

// Round 11
// 777.364 us; speedup vs baseline: 2.5783x; 1.0306x over previous
//
#include <hip/hip_runtime.h>
#include <math.h>

#define HWDIM 128
#define DDIM  512
#define ADIM  512
#define NSTEP 6
#define NPIX  (HWDIM*HWDIM)

typedef short bf16x8 __attribute__((ext_vector_type(8)));
typedef float f32x4 __attribute__((ext_vector_type(4)));

__device__ __forceinline__ ushort f32_bf16_rne(float f) {
  unsigned u = __float_as_uint(f);
  unsigned r = (u + 0x7fffu + ((u >> 16) & 1u)) >> 16;
  return (ushort)r;
}
__device__ __forceinline__ float bf16_f32(ushort h) {
  return __uint_as_float(((unsigned)h) << 16);
}
__device__ __forceinline__ void unpack2(unsigned u, float& a, float& b) {
  a = __uint_as_float(u << 16);
  b = __uint_as_float(u & 0xffff0000u);
}

// ---------------- quantize fp32 -> bf16 (rne) ----------------
__global__ __launch_bounds__(256) void quant_bf16(const float* __restrict__ in,
                                                  ushort* __restrict__ out, int n8) {
  for (int i = blockIdx.x * blockDim.x + threadIdx.x; i < n8; i += gridDim.x * blockDim.x) {
    const float4 v0 = ((const float4*)in)[2 * (size_t)i];
    const float4 v1 = ((const float4*)in)[2 * (size_t)i + 1];
    float x[8] = {v0.x, v0.y, v0.z, v0.w, v1.x, v1.y, v1.z, v1.w};
    ushort h[8];
#pragma unroll
    for (int j = 0; j < 8; ++j) h[j] = f32_bf16_rne(x[j]);
    *(uint4*)(out + (size_t)i * 8) = *(uint4*)h;
  }
}

// ---- weight transpose + split (with scale): W[k][n] -> T[n][k] hi/lo ----
__global__ __launch_bounds__(256) void wsplit(const float* __restrict__ W,
                                              ushort* __restrict__ Thi,
                                              ushort* __restrict__ Tlo, float scale) {
  __shared__ float tile[32][33];
  const int bn = blockIdx.x * 32, bk = blockIdx.y * 32;
  const int tx = threadIdx.x, ty = threadIdx.y;  // block (32,8)
  for (int r = ty; r < 32; r += 8)
    tile[r][tx] = W[(size_t)(bk + r) * 512 + bn + tx];
  __syncthreads();
  for (int r = ty; r < 32; r += 8) {
    const float x = tile[tx][r] * scale;
    const ushort h = f32_bf16_rne(x);
    const ushort l = f32_bf16_rne(x - bf16_f32(h));
    Thi[(size_t)(bn + r) * 512 + bk + tx] = h;
    Tlo[(size_t)(bn + r) * 512 + bk + tx] = l;
  }
}

// ---------------- 2-term split GEMM: A bf16, B hi/lo ----------------
// C[M,N'] = A[M,512] @ B[512,N'], B pre-transposed [n][k] hi/lo.
// 128x128 tile, BK=32, 4 waves, per-wave 4x4 frags of 16x16x32 MFMA, 2 terms.
// LDS tiles [128 rows][32 k] bf16; 16B slot s of row r holds k-group
// s^((r>>1)&3)  (bijective over 8 slots per 8-row group => conflict-free b128).
// OUT_MODE 0: out1 = float[.][512].  OUT_MODE 1: bf16 dual (n<512 -> out1, else out2).
template<int OUT_MODE>
__global__ __launch_bounds__(256, 2) void gemm_a1b2(
    const ushort* __restrict__ A, const ushort* __restrict__ Bh,
    const ushort* __restrict__ Bl, void* __restrict__ out1, void* __restrict__ out2) {
  constexpr int KD = 512;
  __shared__ uint4 smv[1536];  // 24 KB
  char* sm = (char*)smv;
  const int r0 = blockIdx.x * 128;
  const int n0 = blockIdx.y * 128;
  const int tid = threadIdx.x;
  const int wv = tid >> 6, lane = tid & 63;
  const int wr = wv >> 1, wc = wv & 1;

  f32x4 acc[4][4];
#pragma unroll
  for (int a = 0; a < 4; ++a)
#pragma unroll
    for (int b = 0; b < 4; ++b) acc[a][b] = (f32x4){0.f, 0.f, 0.f, 0.f};

  int rowS[2], sS[2];
#pragma unroll
  for (int c = 0; c < 2; ++c) {
    const int idx = c * 256 + tid;
    rowS[c] = idx >> 2;
    sS[c] = (idx & 3) ^ ((rowS[c] >> 1) & 3);
  }
  char* smA  = sm;
  char* smBh = sm + 8192;
  char* smBl = sm + 16384;
  const int ldsWave = wv * 1024;

  for (int k0 = 0; k0 < KD; k0 += 32) {
    __syncthreads();
#pragma unroll
    for (int c = 0; c < 2; ++c) {
      const size_t aoff = (size_t)(r0 + rowS[c]) * 512 + k0 + sS[c] * 8;
      const size_t boff = (size_t)(n0 + rowS[c]) * 512 + k0 + sS[c] * 8;
      const int lds = c * 4096 + ldsWave;
      __builtin_amdgcn_global_load_lds(
          (const __attribute__((address_space(1))) void*)(A + aoff),
          (__attribute__((address_space(3))) void*)(smA + lds), 16, 0, 0);
      __builtin_amdgcn_global_load_lds(
          (const __attribute__((address_space(1))) void*)(Bh + boff),
          (__attribute__((address_space(3))) void*)(smBh + lds), 16, 0, 0);
      __builtin_amdgcn_global_load_lds(
          (const __attribute__((address_space(1))) void*)(Bl + boff),
          (__attribute__((address_space(3))) void*)(smBl + lds), 16, 0, 0);
    }
    __syncthreads();

    const int kq = lane >> 4;
    const int fr = lane & 15;
    bf16x8 ah[4], bh[4], bl[4];
#pragma unroll
    for (int mi = 0; mi < 4; ++mi) {
      const int row = wr * 64 + mi * 16 + fr;
      const int off = row * 64 + ((kq ^ ((row >> 1) & 3)) * 16);
      ah[mi] = *(const bf16x8*)(smA + off);
    }
#pragma unroll
    for (int ni = 0; ni < 4; ++ni) {
      const int row = wc * 64 + ni * 16 + fr;
      const int off = row * 64 + ((kq ^ ((row >> 1) & 3)) * 16);
      bh[ni] = *(const bf16x8*)(smBh + off);
      bl[ni] = *(const bf16x8*)(smBl + off);
    }
#pragma unroll
    for (int mi = 0; mi < 4; ++mi)
#pragma unroll
      for (int ni = 0; ni < 4; ++ni) {
        acc[mi][ni] = __builtin_amdgcn_mfma_f32_16x16x32_bf16(ah[mi], bh[ni], acc[mi][ni], 0, 0, 0);
        acc[mi][ni] = __builtin_amdgcn_mfma_f32_16x16x32_bf16(ah[mi], bl[ni], acc[mi][ni], 0, 0, 0);
      }
  }

  const int fr = lane & 15;
  const int rq = lane >> 4;
  if (OUT_MODE == 1) {
    ushort* op = (ushort*)(n0 >= 512 ? out2 : out1);
    const int cb = (n0 & 511) + wc * 64;
#pragma unroll
    for (int mi = 0; mi < 4; ++mi)
#pragma unroll
      for (int ni = 0; ni < 4; ++ni) {
        const int col = cb + ni * 16 + fr;
#pragma unroll
        for (int r = 0; r < 4; ++r) {
          const int row = r0 + wr * 64 + mi * 16 + rq * 4 + r;
          op[(size_t)row * 512 + col] = f32_bf16_rne(acc[mi][ni][r]);
        }
      }
  } else {
    float* op = (float*)out1;
    const int cb = n0 + wc * 64;
#pragma unroll
    for (int mi = 0; mi < 4; ++mi)
#pragma unroll
      for (int ni = 0; ni < 4; ++ni) {
        const int col = cb + ni * 16 + fr;
#pragma unroll
        for (int r = 0; r < 4; ++r) {
          const int row = r0 + wr * 64 + mi * 16 + rq * 4 + r;
          op[(size_t)row * 512 + col] = acc[mi][ni][r];
        }
      }
  }
}

// ---------------- neighbor attention, t-split: 6 waves = 6 timesteps ----------------
// block = 384 threads; wave w handles timestep w of pixel blockIdx.x.
// Cross-wave t-sum via swizzled LDS; writes summed AO (bf16). 1/6 folded into Wo.
__global__ __launch_bounds__(384) void attn_t6(const float* __restrict__ Qf,
                                               const ushort* __restrict__ Kb,
                                               const ushort* __restrict__ Vb,
                                               ushort* __restrict__ AOsum) {
  __shared__ float red[6][512];
  const int w = threadIdx.x >> 6;      // timestep
  const int lane = threadIdx.x & 63;
  const int p = blockIdx.x;
  const int i = p >> 7, j = p & 127;
  const float scale = 0.04419417382415922f;  // 1/sqrt(512)

  float q[8];
  {
    const float* qp = Qf + (size_t)p * ADIM + lane * 8;
    *(float4*)&q[0] = *(const float4*)(qp);
    *(float4*)&q[4] = *(const float4*)(qp + 4);
  }

  int nb[9];
  {
    const int di[9] = {-1, -1, -1, 0, 0, 0, 1, 1, 1};
    const int dj[9] = {-1, 0, 1, -1, 0, 1, -1, 0, 1};
#pragma unroll
    for (int n = 0; n < 9; ++n) {
      int ni = i + di[n]; ni = ni < 0 ? 0 : (ni > 127 ? 127 : ni);
      int nj = j + dj[n]; nj = nj < 0 ? 0 : (nj > 127 ? 127 : nj);
      nb[n] = ni * HWDIM + nj;
    }
  }

  const ushort* Kt = Kb + (size_t)w * NPIX * ADIM;
  const ushort* Vt = Vb + (size_t)w * NPIX * ADIM;

  float s[9];
#pragma unroll
  for (int n = 0; n < 9; ++n) {
    const uint4 raw = *(const uint4*)(Kt + (size_t)nb[n] * ADIM + lane * 8);
    float kv[8];
    unpack2(raw.x, kv[0], kv[1]);
    unpack2(raw.y, kv[2], kv[3]);
    unpack2(raw.z, kv[4], kv[5]);
    unpack2(raw.w, kv[6], kv[7]);
    float part = 0.f;
#pragma unroll
    for (int c = 0; c < 8; ++c) part = fmaf(q[c], kv[c], part);
#pragma unroll
    for (int off = 32; off > 0; off >>= 1) part += __shfl_xor(part, off);
    s[n] = part * scale;
  }

  float m = s[0];
#pragma unroll
  for (int n = 1; n < 9; ++n) m = fmaxf(m, s[n]);
  float e[9];
  float sum = 0.f;
#pragma unroll
  for (int n = 0; n < 9; ++n) { e[n] = expf(s[n] - m); sum += e[n]; }
  const float inv = 1.f / sum;

  float acc[8];
#pragma unroll
  for (int c = 0; c < 8; ++c) acc[c] = 0.f;
#pragma unroll
  for (int n = 0; n < 9; ++n) {
    const float wt = e[n] * inv;
    const uint4 raw = *(const uint4*)(Vt + (size_t)nb[n] * ADIM + lane * 8);
    float vv[8];
    unpack2(raw.x, vv[0], vv[1]);
    unpack2(raw.y, vv[2], vv[3]);
    unpack2(raw.z, vv[4], vv[5]);
    unpack2(raw.w, vv[6], vv[7]);
#pragma unroll
    for (int c = 0; c < 8; ++c) acc[c] = fmaf(wt, vv[c], acc[c]);
  }

  // swizzled LDS write: 16B chunk c stored at physical chunk c ^ ((c>>3)&7)
  {
    const int c0 = 2 * lane;
    const int sw = (lane >> 2) & 7;
    *(float4*)&red[w][((c0) ^ sw) * 4]     = make_float4(acc[0], acc[1], acc[2], acc[3]);
    *(float4*)&red[w][((c0 + 1) ^ sw) * 4] = make_float4(acc[4], acc[5], acc[6], acc[7]);
  }
  __syncthreads();

  for (int ch = threadIdx.x; ch < 512; ch += 384) {
    const int cs = (((ch >> 2) ^ ((ch >> 5) & 7)) << 2) | (ch & 3);
    const float t = red[0][cs] + red[1][cs] + red[2][cs] +
                    red[3][cs] + red[4][cs] + red[5][cs];
    AOsum[(size_t)p * ADIM + ch] = f32_bf16_rne(t);
  }
}

// ---------------- launch ----------------
extern "C" void kernel_launch(void* const* d_in, const int* in_sizes, int n_in,
                              void* d_out, int out_size, void* d_ws, size_t ws_size,
                              hipStream_t stream) {
  const float* qf   = (const float*)d_in[0];
  const float* hist = (const float*)d_in[1];
  const float* Wq   = (const float*)d_in[2];
  const float* Wk   = (const float*)d_in[3];
  const float* Wv   = (const float*)d_in[4];
  const float* Wo   = (const float*)d_in[5];
  float* out = (float*)d_out;

  const size_t QN  = (size_t)NPIX * ADIM;          // 8,388,608 elems
  const size_t KVN = (size_t)NSTEP * NPIX * ADIM;  // 50,331,648 elems
  const size_t WN  = 512 * 512;

  // workspace ~377 MB (proven bound 448 MiB from round 1)
  size_t off = 0;
  char* base = (char*)d_ws;
  auto alloc = [&](size_t bytes) -> char* {
    char* p = base + off;
    off += (bytes + 255) & ~(size_t)255;
    return p;
  };
  ushort* h_hi   = (ushort*)alloc(KVN * 2);      // full 6-step hist bf16 (100 MB)
  ushort* q_hi   = (ushort*)alloc(QN * 2);
  ushort* wq_hi  = (ushort*)alloc(WN * 2);
  ushort* wq_lo  = (ushort*)alloc(WN * 2);
  ushort* wkv_hi = (ushort*)alloc(2 * WN * 2);   // [1024][512]: rows 0-511 Wk^T, 512-1023 Wv^T
  ushort* wkv_lo = (ushort*)alloc(2 * WN * 2);
  ushort* wo_hi  = (ushort*)alloc(WN * 2);
  ushort* wo_lo  = (ushort*)alloc(WN * 2);
  float*  Qf     = (float*)alloc(QN * 4);
  ushort* Kb     = (ushort*)alloc(KVN * 2);
  ushort* Vb     = (ushort*)alloc(KVN * 2);
  ushort* AOsum  = (ushort*)alloc(QN * 2);

  const float* histBase = hist + (size_t)2 * NPIX * DDIM;  // last 6 of 8 steps

  dim3 wgrid(16, 16), wblk(32, 8);
  wsplit<<<wgrid, wblk, 0, stream>>>(Wq, wq_hi, wq_lo, 1.0f);
  wsplit<<<wgrid, wblk, 0, stream>>>(Wk, wkv_hi, wkv_lo, 1.0f);
  wsplit<<<wgrid, wblk, 0, stream>>>(Wv, wkv_hi + 512 * 512, wkv_lo + 512 * 512, 1.0f);
  wsplit<<<wgrid, wblk, 0, stream>>>(Wo, wo_hi, wo_lo, 1.0f / (float)NSTEP);

  // quantize Q features + full history in two dispatches
  quant_bf16<<<1024, 256, 0, stream>>>(qf, q_hi, (int)(QN / 8));
  quant_bf16<<<2048, 256, 0, stream>>>(histBase, h_hi, (int)(KVN / 8));

  // Q projection (fp32 out)
  gemm_a1b2<0><<<dim3(NPIX / 128, 4), 256, 0, stream>>>(q_hi, wq_hi, wq_lo, Qf, nullptr);

  // single fused K|V projection over all 6 timesteps:
  // A = [98304][512], B = [1024][512] hi/lo, outputs row-major [t*NPIX+pix][512]
  gemm_a1b2<1><<<dim3(NSTEP * NPIX / 128, 8), 256, 0, stream>>>(h_hi, wkv_hi, wkv_lo, Kb, Vb);

  // attention (t-parallel, block-level t-sum)
  attn_t6<<<NPIX, 384, 0, stream>>>(Qf, Kb, Vb, AOsum);

  // output projection (1/6 folded into wo split)
  gemm_a1b2<0><<<dim3(NPIX / 128, 4), 256, 0, stream>>>(AOsum, wo_hi, wo_lo, out, nullptr);
}